// Round 2
// baseline (3360.616 us; speedup 1.0000x reference)
//
#include <hip/hip_runtime.h>
#include <math.h>

typedef __attribute__((ext_vector_type(8))) short bf16x8;
typedef __attribute__((ext_vector_type(4))) float f32x4;

#define BB 64
#define TT 2048
#define RR 256
#define BLK 24
#define NTHR 512
#define HB_PAD 776   // 768 + 8: rows 16B-aligned, stride 388 dw = 4 mod 32 -> 2-way (free)
#define HW_PAD 264   // 256 + 8: same properties
#define C4_PAD 264   // stride 264 f32: 264%32=8 -> max 2-way on writes (free)

#define MFMA(a, b, c) __builtin_amdgcn_mfma_f32_16x16x32_bf16((a), (b), (c), 0, 0, 0)

__device__ __forceinline__ unsigned short f2bf(float f) {
    unsigned u = __float_as_uint(f);
    return (unsigned short)((u + 0x7FFFu + ((u >> 16) & 1u)) >> 16);  // RNE
}
__device__ __forceinline__ float bf2f(unsigned short h) {
    return __uint_as_float(((unsigned)h) << 16);
}
// Branch-free tanh: 1 - 2/(1+e^{2x}).
__device__ __forceinline__ float fast_tanh(float x) {
    float e = __expf(2.0f * x);
    return 1.0f - 2.0f * __builtin_amdgcn_rcpf(1.0f + e);
}

// ---- Pre-pass: pack tw[tap]*W_fb[tap] into MFMA B-fragment order (bf16) ----
// Layout: chunk c = (tap*8 + kt)*16 + nt; element = c*512 + lane*8 (ushorts).
// Fragment: lane l holds B[k = 32*kt + 8*(l>>4) + j][n = 16*nt + (l&15)], j=0..7.
__global__ void pack_weights(const float* __restrict__ W_fb,
                             const float* __restrict__ tapw,
                             unsigned short* __restrict__ bp) {
    int gid = blockIdx.x * 256 + threadIdx.x;      // 40960 threads
    int l = gid & 63, c = gid >> 6;                // c: 0..639
    int tap = c >> 7;
    int rem = c & 127;
    int kt = rem >> 4, nt = rem & 15;

    float v0 = tapw[0], v1 = tapw[1], v2 = tapw[2], v3 = tapw[3], v4 = tapw[4];
    float mx = fmaxf(fmaxf(fmaxf(v0, v1), fmaxf(v2, v3)), v4);
    float e0 = expf(v0 - mx), e1 = expf(v1 - mx), e2 = expf(v2 - mx),
          e3 = expf(v3 - mx), e4 = expf(v4 - mx);
    float inv = 1.0f / (e0 + e1 + e2 + e3 + e4);
    float tws[5] = {e0 * inv, e1 * inv, e2 * inv, e3 * inv, e4 * inv};
    float tw = tws[tap];

    int kbase = 32 * kt + 8 * (l >> 4);
    int n = 16 * nt + (l & 15);
    const float* W = W_fb + tap * 65536;
    unsigned short t[8];
#pragma unroll
    for (int j = 0; j < 8; ++j) t[j] = f2bf(tw * W[(kbase + j) * 256 + n]);
    uint4 o;
    o.x = (unsigned)t[0] | ((unsigned)t[1] << 16);
    o.y = (unsigned)t[2] | ((unsigned)t[3] << 16);
    o.z = (unsigned)t[4] | ((unsigned)t[5] << 16);
    o.w = (unsigned)t[6] | ((unsigned)t[7] << 16);
    *(uint4*)(bp + (size_t)(c * 64 + l) * 8) = o;
}

// Per-step update for waves 0-3: combine tap1 (c1a/c1b regs), tap4 (c4buf LDS),
// far+bias+drive (Gl LDS); leaky-tanh; write h to hwinb ring (hi/lo) + hob.
#define UPDATE(u_) do {                                                          \
    const int t_ = t4 + (u_);                                                    \
    const int jj_ = t_ - t0;                                                     \
    const int wsl_ = t_ & 7;                                                     \
    float hn_[4];                                                                \
    _Pragma("unroll")                                                            \
    for (int nt = 0; nt < 4; ++nt) {                                             \
        int s_ = 64 * w4 + 16 * nt + l15;                                        \
        float f_ = (c1a[nt][0] + c1b[nt][0]) + c4buf[(u_)][s_] + Gl[jj_][s_];    \
        hn_[nt] = 0.9f * hp[nt] + 0.1f * fast_tanh(f_);                          \
        hp[nt] = hn_[nt];                                                        \
    }                                                                            \
    if (lane < 16) {                                                             \
        _Pragma("unroll")                                                        \
        for (int nt = 0; nt < 4; ++nt) {                                         \
            int s_ = 64 * w4 + 16 * nt + l15;                                    \
            unsigned short hh_ = f2bf(hn_[nt]);                                  \
            hwinb[wsl_][0][s_] = hh_;                                            \
            hwinb[wsl_][1][s_] = f2bf(hn_[nt] - bf2f(hh_));                      \
            hob[jj_][s_] = hn_[nt];                                              \
        }                                                                        \
    }                                                                            \
} while (0)

// ---- Main kernel: one WG per batch, 8 waves ----
// R2 changes vs 2818us R1:
//  (1) wave specialization in the step loop: waves 0-3 do tap d=1 (N=64 cols each),
//      waves 4-7 do tap d=4 (N=64 each, once per 4-step sub-block, result passed
//      via c4buf LDS). Redundant A-operand LDS reads drop 2x (8 waves -> 4 waves
//      reading the full h hi/lo per step). Cost: +1 barrier per sub-block.
//  (2) far-GEMM B-fragment prefetch depth 3 (was 1) to cover L2 latency.
__global__ __launch_bounds__(NTHR, 1)
void reservoir_mfma(const float* __restrict__ x,
                    const float* __restrict__ W_in,
                    const float* __restrict__ bias,
                    const unsigned short* __restrict__ bp,
                    float* __restrict__ out)
{
    const int b    = blockIdx.x;
    const int tid  = threadIdx.x;
    const int lane = tid & 63;
    const int w    = tid >> 6;
    const int l15  = lane & 15;
    const int quad = lane >> 4;
    const int w4   = w & 3;          // column-group index within role (0..3)

    __shared__ float xs[TT];                             // 8 KB
    __shared__ unsigned short hwinb[8][2][HW_PAD];       // 8.25 KB: h ring, bf16 hi/lo
    __shared__ unsigned short hbcb[BLK][2][HB_PAD];      // 72.8 KB: far history hi/lo
    __shared__ float Gl[BLK][257];                       // 24.1 KB: far-tap + drive + bias
    __shared__ float hob[BLK][RR];                       // 24 KB: block h output buffer
    __shared__ float c4buf[4][C4_PAD];                   // 4.1 KB: tap4 per-step results

    for (int i = tid; i < TT; i += NTHR) xs[i] = x[b * TT + i];
    {
        unsigned* hz = (unsigned*)&hwinb[0][0][0];
        for (int i = tid; i < 8 * 2 * HW_PAD / 2; i += NTHR) hz[i] = 0u;
    }

    const bf16x8* bpv = (const bf16x8*)bp;
    // Wave-specialized resident B frags: waves 0-3 tap d=1, waves 4-7 tap d=4;
    // each wave owns 4 column tiles nt = 4*w4 .. 4*w4+3.  8*4 frags = 128 regs.
    bf16x8 bres[8][4];
    {
        const int tapsel = (w < 4) ? 0 : 1;
#pragma unroll
        for (int kt = 0; kt < 8; ++kt)
#pragma unroll
            for (int u = 0; u < 4; ++u)
                bres[kt][u] = bpv[((tapsel * 8 + kt) * 16 + 4 * w4 + u) * 64 + lane];
    }

    // far-GEMM writeback mapping (2 cols per wave, all 8 waves)
    const int s0g = 32 * w + l15, s1g = s0g + 16;
    const float win0 = W_in[s0g], win1 = W_in[s1g];
    const float bi0 = bias[s0g], bi1 = bias[s1g];
    float hp[4] = {0.f, 0.f, 0.f, 0.f};

    const float* outr = out + (size_t)b * TT * RR;
    float*       outw = out + (size_t)b * TT * RR;

    __syncthreads();

    for (int t0 = 0; t0 < TT; t0 += BLK) {
        // ---- stage far history (taps 24/96/168) into hbcb, bf16 hi/lo ----
        // tap-24 rows come from previous block's hob (still resident in LDS).
#pragma unroll
        for (int it = 0; it < 9; ++it) {                  // 9*512 = 4608 = 24*768/4
            int i = it * NTHR + tid;
            int j = i / 192;
            int p = i - j * 192;
            int r = 4 * p;
            int kf = r >> 8, rr = r & 255;
            float4 v = {0.f, 0.f, 0.f, 0.f};
            if (kf == 0) {
                if (t0 > 0) v = *(const float4*)&hob[j][rr];
            } else {
                int dk = (kf == 1) ? 96 : 168;
                int tt = t0 + j - dk;
                if (tt >= 0) v = *(const float4*)(outr + (size_t)tt * RR + rr);
            }
            unsigned short h0 = f2bf(v.x), h1 = f2bf(v.y), h2 = f2bf(v.z), h3 = f2bf(v.w);
            unsigned short q0 = f2bf(v.x - bf2f(h0)), q1 = f2bf(v.y - bf2f(h1)),
                           q2 = f2bf(v.z - bf2f(h2)), q3 = f2bf(v.w - bf2f(h3));
            uint2 H = { (unsigned)h0 | ((unsigned)h1 << 16), (unsigned)h2 | ((unsigned)h3 << 16) };
            uint2 Q = { (unsigned)q0 | ((unsigned)q1 << 16), (unsigned)q2 | ((unsigned)q3 << 16) };
            *(uint2*)&hbcb[j][0][r] = H;
            *(uint2*)&hbcb[j][1][r] = Q;
        }
        __syncthreads();

        // ---- far GEMM: C[24 j][32 s/wave] over K=768, hi+lo A, var-split accs,
        //      B-fragment prefetch depth 3 ----
        f32x4 zf = {0.f, 0.f, 0.f, 0.f};
        f32x4 cf00a = zf, cf01a = zf, cf10a = zf, cf11a = zf;
        f32x4 cf00b = zf, cf01b = zf, cf10b = zf, cf11b = zf;
        const int r0a = l15;              // m-tile 0: j = 0..15
        const int r1a = 16 + (l15 & 7);   // m-tile 1: j = 16..23 (dup rows discarded)
        const int cw0 = 2 * w, cw1 = 2 * w + 1;
        bf16x8 q0A = bpv[((16 + 0) * 16 + cw0) * 64 + lane];
        bf16x8 q0B = bpv[((16 + 0) * 16 + cw1) * 64 + lane];
        bf16x8 q1A = bpv[((16 + 1) * 16 + cw0) * 64 + lane];
        bf16x8 q1B = bpv[((16 + 1) * 16 + cw1) * 64 + lane];
        bf16x8 q2A = bpv[((16 + 2) * 16 + cw0) * 64 + lane];
        bf16x8 q2B = bpv[((16 + 2) * 16 + cw1) * 64 + lane];
#pragma unroll 1
        for (int g = 0; g < 8; ++g) {
            const int base = 3 * g;
            {
                int ro = 32 * base + 8 * quad;
                bf16x8 a00 = *(const bf16x8*)&hbcb[r0a][0][ro];
                bf16x8 a01 = *(const bf16x8*)&hbcb[r0a][1][ro];
                bf16x8 a10 = *(const bf16x8*)&hbcb[r1a][0][ro];
                bf16x8 a11 = *(const bf16x8*)&hbcb[r1a][1][ro];
                cf00a = MFMA(a00, q0A, cf00a); cf01a = MFMA(a00, q0B, cf01a);
                cf10a = MFMA(a10, q0A, cf10a); cf11a = MFMA(a10, q0B, cf11a);
                cf00b = MFMA(a01, q0A, cf00b); cf01b = MFMA(a01, q0B, cf01b);
                cf10b = MFMA(a11, q0A, cf10b); cf11b = MFMA(a11, q0B, cf11b);
                int nf = base + 3; if (nf > 23) nf = 23;
                q0A = bpv[((16 + nf) * 16 + cw0) * 64 + lane];
                q0B = bpv[((16 + nf) * 16 + cw1) * 64 + lane];
            }
            {
                int ro = 32 * (base + 1) + 8 * quad;
                bf16x8 a00 = *(const bf16x8*)&hbcb[r0a][0][ro];
                bf16x8 a01 = *(const bf16x8*)&hbcb[r0a][1][ro];
                bf16x8 a10 = *(const bf16x8*)&hbcb[r1a][0][ro];
                bf16x8 a11 = *(const bf16x8*)&hbcb[r1a][1][ro];
                cf00a = MFMA(a00, q1A, cf00a); cf01a = MFMA(a00, q1B, cf01a);
                cf10a = MFMA(a10, q1A, cf10a); cf11a = MFMA(a10, q1B, cf11a);
                cf00b = MFMA(a01, q1A, cf00b); cf01b = MFMA(a01, q1B, cf01b);
                cf10b = MFMA(a11, q1A, cf10b); cf11b = MFMA(a11, q1B, cf11b);
                int nf = base + 4; if (nf > 23) nf = 23;
                q1A = bpv[((16 + nf) * 16 + cw0) * 64 + lane];
                q1B = bpv[((16 + nf) * 16 + cw1) * 64 + lane];
            }
            {
                int ro = 32 * (base + 2) + 8 * quad;
                bf16x8 a00 = *(const bf16x8*)&hbcb[r0a][0][ro];
                bf16x8 a01 = *(const bf16x8*)&hbcb[r0a][1][ro];
                bf16x8 a10 = *(const bf16x8*)&hbcb[r1a][0][ro];
                bf16x8 a11 = *(const bf16x8*)&hbcb[r1a][1][ro];
                cf00a = MFMA(a00, q2A, cf00a); cf01a = MFMA(a00, q2B, cf01a);
                cf10a = MFMA(a10, q2A, cf10a); cf11a = MFMA(a10, q2B, cf11a);
                cf00b = MFMA(a01, q2A, cf00b); cf01b = MFMA(a01, q2B, cf01b);
                cf10b = MFMA(a11, q2A, cf10b); cf11b = MFMA(a11, q2B, cf11b);
                int nf = base + 5; if (nf > 23) nf = 23;
                q2A = bpv[((16 + nf) * 16 + cw0) * 64 + lane];
                q2B = bpv[((16 + nf) * 16 + cw1) * 64 + lane];
            }
        }
        f32x4 cf00 = cf00a + cf00b, cf01 = cf01a + cf01b;
        f32x4 cf10 = cf10a + cf10b, cf11 = cf11a + cf11b;
        // writeback + fold bias and drive: Gl[j][s] = far[j][s] + bias[s] + x[t0+j]*Win[s]
#pragma unroll
        for (int i = 0; i < 4; ++i) {
            int j0 = 4 * quad + i;
            int tx0 = t0 + j0; float xv0 = xs[tx0 < TT ? tx0 : TT - 1];
            Gl[j0][s0g] = cf00[i] + bi0 + xv0 * win0;
            Gl[j0][s1g] = cf01[i] + bi1 + xv0 * win1;
            int j1 = 16 + 4 * quad + i;
            if (j1 < BLK) {
                int tx1 = t0 + j1; float xv1 = xs[tx1 < TT ? tx1 : TT - 1];
                Gl[j1][s0g] = cf10[i] + bi0 + xv1 * win0;
                Gl[j1][s1g] = cf11[i] + bi1 + xv1 * win1;
            }
        }
        __syncthreads();

        // ---- sequential sub-blocks of 4 steps, wave-specialized ----
        const int tend = (t0 + BLK < TT) ? (t0 + BLK) : TT;
#pragma unroll 1
        for (int t4 = t0; t4 < tend; t4 += 4) {
            f32x4 c1a[4], c1b[4];
            if (w >= 4) {
                // tap d=4, M=4: A rows r hold h(t4-4+(r&3)); C reg i = step i (all quads)
                f32x4 ca[4], cb[4];
#pragma unroll
                for (int nt = 0; nt < 4; ++nt) { ca[nt] = zf; cb[nt] = zf; }
                const int sl = (t4 - 4 + (l15 & 3)) & 7;
#pragma unroll
                for (int kt = 0; kt < 8; ++kt) {
                    int ro = 32 * kt + 8 * quad;
                    bf16x8 a0 = *(const bf16x8*)&hwinb[sl][0][ro];
                    bf16x8 a1 = *(const bf16x8*)&hwinb[sl][1][ro];
#pragma unroll
                    for (int nt = 0; nt < 4; ++nt) {
                        ca[nt] = MFMA(a0, bres[kt][nt], ca[nt]);
                        cb[nt] = MFMA(a1, bres[kt][nt], cb[nt]);
                    }
                }
                // quad q publishes step q's contribution (C reg q) for its 4 col tiles
#pragma unroll
                for (int nt = 0; nt < 4; ++nt) {
                    f32x4 c4 = ca[nt] + cb[nt];
                    float v = (quad == 0) ? c4[0] : (quad == 1) ? c4[1]
                            : (quad == 2) ? c4[2] : c4[3];
                    c4buf[quad][64 * w4 + 16 * nt + l15] = v;
                }
            } else {
                // tap d=1 MFMA for step u=0 (A = h(t4-1), broadcast rows)
                const int sp = (t4 - 1) & 7;
#pragma unroll
                for (int nt = 0; nt < 4; ++nt) { c1a[nt] = zf; c1b[nt] = zf; }
#pragma unroll
                for (int kt = 0; kt < 8; ++kt) {
                    int ro = 32 * kt + 8 * quad;
                    bf16x8 a0 = *(const bf16x8*)&hwinb[sp][0][ro];
                    bf16x8 a1 = *(const bf16x8*)&hwinb[sp][1][ro];
#pragma unroll
                    for (int nt = 0; nt < 4; ++nt) {
                        c1a[nt] = MFMA(a0, bres[kt][nt], c1a[nt]);
                        c1b[nt] = MFMA(a1, bres[kt][nt], c1b[nt]);
                    }
                }
            }
            __syncthreads();   // c4buf visible for this sub-block
            if (w < 4) { UPDATE(0); }
            __syncthreads();   // end of step 0
#pragma unroll
            for (int u = 1; u < 4; ++u) {
                if (w < 4) {
                    const int sp = (t4 + u - 1) & 7;
#pragma unroll
                    for (int nt = 0; nt < 4; ++nt) { c1a[nt] = zf; c1b[nt] = zf; }
#pragma unroll
                    for (int kt = 0; kt < 8; ++kt) {
                        int ro = 32 * kt + 8 * quad;
                        bf16x8 a0 = *(const bf16x8*)&hwinb[sp][0][ro];
                        bf16x8 a1 = *(const bf16x8*)&hwinb[sp][1][ro];
#pragma unroll
                        for (int nt = 0; nt < 4; ++nt) {
                            c1a[nt] = MFMA(a0, bres[kt][nt], c1a[nt]);
                            c1b[nt] = MFMA(a1, bres[kt][nt], c1b[nt]);
                        }
                    }
                    UPDATE(u);
                }
                __syncthreads();  // end of step u
            }
        }

        // ---- flush hob -> out, coalesced float4 (drains at next block's barrier) ----
        {
            const int nf4 = (tend - t0) * (RR / 4);       // 1536, or 512 in last block
            const float4* src = (const float4*)&hob[0][0];
            float4* dst = (float4*)(outw + (size_t)t0 * RR);
#pragma unroll
            for (int it = 0; it < 3; ++it) {
                int idx = it * NTHR + tid;
                if (idx < nf4) dst[idx] = src[idx];
            }
        }
    }
}

extern "C" void kernel_launch(void* const* d_in, const int* in_sizes, int n_in,
                              void* d_out, int out_size, void* d_ws, size_t ws_size,
                              hipStream_t stream) {
    const float* x    = (const float*)d_in[0];   // (64, 2048, 1)
    const float* W_in = (const float*)d_in[1];   // (256, 1)
    const float* W_fb = (const float*)d_in[2];   // (5, 256, 256)
    const float* tapw = (const float*)d_in[3];   // (5,)
    const float* bias = (const float*)d_in[4];   // (256,)
    float* out = (float*)d_out;                  // (64, 2048, 256)
    unsigned short* bp = (unsigned short*)d_ws;  // 640 KB packed bf16 B-fragments

    pack_weights<<<160, 256, 0, stream>>>(W_fb, tapw, bp);
    reservoir_mfma<<<BB, NTHR, 0, stream>>>(x, W_in, bias, bp, out);
}

// Round 3
// 2213.591 us; speedup vs baseline: 1.5182x; 1.5182x over previous
//
#include <hip/hip_runtime.h>
#include <math.h>

typedef __attribute__((ext_vector_type(8))) short bf16x8;
typedef __attribute__((ext_vector_type(4))) float f32x4;

#define BB 64
#define TT 2048
#define RR 256
#define BLK 24
#define NTHR 512
#define HB_PAD 776   // 768 + 8: rows 16B-aligned, stride 388 dw = 4 mod 32 -> 2-way (free)
#define HW_PAD 264   // 256 + 8: same properties

#define MFMA(a, b, c) __builtin_amdgcn_mfma_f32_16x16x32_bf16((a), (b), (c), 0, 0, 0)

__device__ __forceinline__ unsigned short f2bf(float f) {
    unsigned u = __float_as_uint(f);
    return (unsigned short)((u + 0x7FFFu + ((u >> 16) & 1u)) >> 16);  // RNE
}
__device__ __forceinline__ float bf2f(unsigned short h) {
    return __uint_as_float(((unsigned)h) << 16);
}
// Branch-free tanh: 1 - 2/(1+e^{2x}).
__device__ __forceinline__ float fast_tanh(float x) {
    float e = __expf(2.0f * x);
    return 1.0f - 2.0f * __builtin_amdgcn_rcpf(1.0f + e);
}

// ---- Pre-pass: pack tw[tap]*W_fb[tap] into MFMA B-fragment order (bf16) ----
// Layout: chunk c = (tap*8 + kt)*16 + nt; element = c*512 + lane*8 (ushorts).
// Fragment: lane l holds B[k = 32*kt + 8*(l>>4) + j][n = 16*nt + (l&15)], j=0..7.
__global__ void pack_weights(const float* __restrict__ W_fb,
                             const float* __restrict__ tapw,
                             unsigned short* __restrict__ bp) {
    int gid = blockIdx.x * 256 + threadIdx.x;      // 40960 threads
    int l = gid & 63, c = gid >> 6;                // c: 0..639
    int tap = c >> 7;
    int rem = c & 127;
    int kt = rem >> 4, nt = rem & 15;

    float v0 = tapw[0], v1 = tapw[1], v2 = tapw[2], v3 = tapw[3], v4 = tapw[4];
    float mx = fmaxf(fmaxf(fmaxf(v0, v1), fmaxf(v2, v3)), v4);
    float e0 = expf(v0 - mx), e1 = expf(v1 - mx), e2 = expf(v2 - mx),
          e3 = expf(v3 - mx), e4 = expf(v4 - mx);
    float inv = 1.0f / (e0 + e1 + e2 + e3 + e4);
    float tws[5] = {e0 * inv, e1 * inv, e2 * inv, e3 * inv, e4 * inv};
    float tw = tws[tap];

    int kbase = 32 * kt + 8 * (l >> 4);
    int n = 16 * nt + (l & 15);
    const float* W = W_fb + tap * 65536;
    unsigned short t[8];
#pragma unroll
    for (int j = 0; j < 8; ++j) t[j] = f2bf(tw * W[(kbase + j) * 256 + n]);
    uint4 o;
    o.x = (unsigned)t[0] | ((unsigned)t[1] << 16);
    o.y = (unsigned)t[2] | ((unsigned)t[3] << 16);
    o.z = (unsigned)t[4] | ((unsigned)t[5] << 16);
    o.w = (unsigned)t[6] | ((unsigned)t[7] << 16);
    *(uint4*)(bp + (size_t)(c * 64 + l) * 8) = o;
}

// ---- Main kernel: one WG per batch, 8 waves; wave w owns s in [32w, 32w+32) ----
// R3 changes vs 2818us R1 (R2's specialization reverted — it was a wash on MFMA
// pipe time and hurt latency hiding):
//  Row-packing of the hi/lo split into the unused M-rows of each MFMA, with
//  bit-identical arithmetic (same products, same final adds):
//  (1) tap1: A row0 = h_hi, row1 = h_lo (lane reads hwinb[sp][l15&1]); result
//      = C[0] + C[1] on lanes<16. 2 chains -> 1 chain: 256 -> 128 MFMA/step/CU,
//      A-reads halved.
//  (2) tap4: rows 0-3 = steps hi, rows 4-7 = steps lo (var = (l15>>2)&1);
//      full result = C[u] + shfl_xor(C[u], 16). 64 -> 32 MFMA/step/CU.
//  (3) far tile1 (j=16..23): rows 0-7 = hi, rows 8-15 = lo (var = (l15>>3)&1);
//      full = C[i] + shfl_xor(C[i], 32). 8 -> 6 MFMA/ft/wave.
//  Total MFMA: 384 -> 208 per step per CU.
__global__ __launch_bounds__(NTHR, 1)
void reservoir_mfma(const float* __restrict__ x,
                    const float* __restrict__ W_in,
                    const float* __restrict__ bias,
                    const unsigned short* __restrict__ bp,
                    float* __restrict__ out)
{
    const int b    = blockIdx.x;
    const int tid  = threadIdx.x;
    const int lane = tid & 63;
    const int w    = tid >> 6;
    const int l15  = lane & 15;
    const int quad = lane >> 4;

    __shared__ float xs[TT];                             // 8 KB
    __shared__ unsigned short hwinb[8][2][HW_PAD];       // 8.25 KB: h ring, bf16 hi/lo
    __shared__ unsigned short hbcb[BLK][2][HB_PAD];      // 72.8 KB: far history hi/lo
    __shared__ float Gl[BLK][257];                       // 24.1 KB: far-tap + drive + bias
    __shared__ float hob[BLK][RR];                       // 24 KB: block h output buffer

    for (int i = tid; i < TT; i += NTHR) xs[i] = x[b * TT + i];
    {
        unsigned* hz = (unsigned*)&hwinb[0][0][0];
        for (int i = tid; i < 8 * 2 * HW_PAD / 2; i += NTHR) hz[i] = 0u;
    }

    // Resident B-fragments: tap d=1 (b1) and d=4 (b4). 128 VGPRs total.
    const bf16x8* bpv = (const bf16x8*)bp;
    bf16x8 b1[8][2], b4[8][2];
#pragma unroll
    for (int kt = 0; kt < 8; ++kt)
#pragma unroll
        for (int u = 0; u < 2; ++u) {
            int nt = 2 * w + u;
            b1[kt][u] = bpv[((0 * 8 + kt) * 16 + nt) * 64 + lane];
            b4[kt][u] = bpv[((1 * 8 + kt) * 16 + nt) * 64 + lane];
        }

    const int s0g = 32 * w + l15, s1g = s0g + 16;
    const float win0 = W_in[s0g], win1 = W_in[s1g];
    const float bi0 = bias[s0g], bi1 = bias[s1g];
    float hp0 = 0.0f, hp1 = 0.0f;

    const float* outr = out + (size_t)b * TT * RR;
    float*       outw = out + (size_t)b * TT * RR;

    // Row-packed A-operand base pointers (var folded into the lane index):
    // tap1: row parity selects hi/lo
    const unsigned short* hw1v = &hwinb[0][l15 & 1][0];
    // tap4: rows 0-3 steps (hi), rows 4-7 steps (lo)
    const unsigned short* hw4v = &hwinb[0][(l15 >> 2) & 1][0];
    // far tile1: rows 0-7 = j 16..23 hi, rows 8-15 = j 16..23 lo
    const unsigned short* fa1 = &hbcb[16 + (l15 & 7)][(l15 >> 3) & 1][0];
    const size_t HWSLOT = 2 * HW_PAD;   // ushorts per hwinb slot

    __syncthreads();

    for (int t0 = 0; t0 < TT; t0 += BLK) {
        // ---- stage far history (taps 24/96/168) into hbcb, bf16 hi/lo ----
        // tap-24 rows come from previous block's hob (still resident in LDS).
#pragma unroll
        for (int it = 0; it < 9; ++it) {                  // 9*512 = 4608 = 24*768/4
            int i = it * NTHR + tid;
            int j = i / 192;
            int p = i - j * 192;
            int r = 4 * p;
            int kf = r >> 8, rr = r & 255;
            float4 v = {0.f, 0.f, 0.f, 0.f};
            if (kf == 0) {
                if (t0 > 0) v = *(const float4*)&hob[j][rr];
            } else {
                int dk = (kf == 1) ? 96 : 168;
                int tt = t0 + j - dk;
                if (tt >= 0) v = *(const float4*)(outr + (size_t)tt * RR + rr);
            }
            unsigned short h0 = f2bf(v.x), h1 = f2bf(v.y), h2 = f2bf(v.z), h3 = f2bf(v.w);
            unsigned short q0 = f2bf(v.x - bf2f(h0)), q1 = f2bf(v.y - bf2f(h1)),
                           q2 = f2bf(v.z - bf2f(h2)), q3 = f2bf(v.w - bf2f(h3));
            uint2 H = { (unsigned)h0 | ((unsigned)h1 << 16), (unsigned)h2 | ((unsigned)h3 << 16) };
            uint2 Q = { (unsigned)q0 | ((unsigned)q1 << 16), (unsigned)q2 | ((unsigned)q3 << 16) };
            *(uint2*)&hbcb[j][0][r] = H;
            *(uint2*)&hbcb[j][1][r] = Q;
        }
        __syncthreads();

        // ---- far GEMM: C[24 j][32 s/wave] over K=768; tile0 hi+lo chains,
        //      tile1 row-packed (6 MFMA/ft) ----
        f32x4 zf = {0.f, 0.f, 0.f, 0.f};
        f32x4 cf00a = zf, cf01a = zf, cf00b = zf, cf01b = zf, cf10 = zf, cf11 = zf;
        const int r0a = l15;              // m-tile 0: j = 0..15
        bf16x8 nB0 = bpv[((16 + 0) * 16 + 2 * w + 0) * 64 + lane];
        bf16x8 nB1 = bpv[((16 + 0) * 16 + 2 * w + 1) * 64 + lane];
#pragma unroll 1
        for (int ft = 0; ft < 24; ++ft) {
            bf16x8 B0 = nB0, B1 = nB1;
            int nf = (ft < 23) ? ft + 1 : 23;             // prefetch next (dup at end)
            nB0 = bpv[((16 + nf) * 16 + 2 * w + 0) * 64 + lane];
            nB1 = bpv[((16 + nf) * 16 + 2 * w + 1) * 64 + lane];
            int ro = 32 * ft + 8 * quad;
            bf16x8 a00 = *(const bf16x8*)&hbcb[r0a][0][ro];
            bf16x8 a01 = *(const bf16x8*)&hbcb[r0a][1][ro];
            bf16x8 a1  = *(const bf16x8*)&fa1[ro];
            cf00a = MFMA(a00, B0, cf00a); cf01a = MFMA(a00, B1, cf01a);
            cf00b = MFMA(a01, B0, cf00b); cf01b = MFMA(a01, B1, cf01b);
            cf10  = MFMA(a1,  B0, cf10);  cf11  = MFMA(a1,  B1, cf11);
        }
        f32x4 cf00 = cf00a + cf00b, cf01 = cf01a + cf01b;
        // tile1 full = hi (quads 0,1) + lo (quads 2,3): combine across lane^32
        float cf10f[4], cf11f[4];
#pragma unroll
        for (int i = 0; i < 4; ++i) {
            cf10f[i] = cf10[i] + __shfl_xor(cf10[i], 32, 64);
            cf11f[i] = cf11[i] + __shfl_xor(cf11[i], 32, 64);
        }
        // writeback + fold bias and drive: Gl[j][s] = far[j][s] + bias[s] + x[t0+j]*Win[s]
#pragma unroll
        for (int i = 0; i < 4; ++i) {
            int j0 = 4 * quad + i;
            int tx0 = t0 + j0; float xv0 = xs[tx0 < TT ? tx0 : TT - 1];
            Gl[j0][s0g] = cf00[i] + bi0 + xv0 * win0;
            Gl[j0][s1g] = cf01[i] + bi1 + xv0 * win1;
            int j1 = 16 + 4 * quad + i;
            if (j1 < BLK) {
                int tx1 = t0 + j1; float xv1 = xs[tx1 < TT ? tx1 : TT - 1];
                Gl[j1][s0g] = cf10f[i] + bi0 + xv1 * win0;
                Gl[j1][s1g] = cf11f[i] + bi1 + xv1 * win1;
            }
        }
        __syncthreads();

        // ---- sequential sub-blocks of 4 steps ----
        const int tend = (t0 + BLK < TT) ? (t0 + BLK) : TT;
#pragma unroll 1
        for (int t4 = t0; t4 < tend; t4 += 4) {
            // tap d=4, row-packed: rows 0-3 = h(t4-4+u) hi, rows 4-7 = lo.
            // C (quad0 regs) = hi steps, (quad1 regs) = lo steps.
            f32x4 c40 = zf, c41 = zf;
            const int sl = (t4 - 4 + (l15 & 3)) & 7;
            const unsigned short* hw4 = hw4v + (size_t)sl * HWSLOT;
#pragma unroll
            for (int kt = 0; kt < 8; ++kt) {
                int ro = 32 * kt + 8 * quad;
                bf16x8 a = *(const bf16x8*)&hw4[ro];
                c40 = MFMA(a, b4[kt][0], c40);
                c41 = MFMA(a, b4[kt][1], c41);
            }
            float c40f[4], c41f[4];
#pragma unroll
            for (int u2 = 0; u2 < 4; ++u2) {
                c40f[u2] = c40[u2] + __shfl_xor(c40[u2], 16, 64);
                c41f[u2] = c41[u2] + __shfl_xor(c41[u2], 16, 64);
            }
            // 4 sequential steps; tap d=1 per step, row-packed hi/lo (1 chain/nt)
#pragma unroll
            for (int u = 0; u < 4; ++u) {
                const int t = t4 + u;
                const int sp = (t - 1) & 7;
                const unsigned short* hw1 = hw1v + (size_t)sp * HWSLOT;
                f32x4 c10 = zf, c11 = zf;
#pragma unroll
                for (int kt = 0; kt < 8; ++kt) {
                    int ro = 32 * kt + 8 * quad;
                    bf16x8 a = *(const bf16x8*)&hw1[ro];
                    c10 = MFMA(a, b1[kt][0], c10);
                    c11 = MFMA(a, b1[kt][1], c11);
                }
                // update (valid on lanes 0..15: rows 0,1 -> quad0 regs 0,1)
                int jj = t - t0;
                float f0 = (c10[0] + c10[1]) + c40f[u] + Gl[jj][s0g];
                float f1 = (c11[0] + c11[1]) + c41f[u] + Gl[jj][s1g];
                float h0 = 0.9f * hp0 + 0.1f * fast_tanh(f0);
                float h1 = 0.9f * hp1 + 0.1f * fast_tanh(f1);
                hp0 = h0; hp1 = h1;
                const int wsl = t & 7;
                if (lane < 16) {
                    unsigned short hh0 = f2bf(h0), hh1 = f2bf(h1);
                    hwinb[wsl][0][s0g] = hh0;
                    hwinb[wsl][0][s1g] = hh1;
                    hwinb[wsl][1][s0g] = f2bf(h0 - bf2f(hh0));
                    hwinb[wsl][1][s1g] = f2bf(h1 - bf2f(hh1));
                    hob[jj][s0g] = h0;   // LDS only; global store deferred to flush
                    hob[jj][s1g] = h1;
                }
                __syncthreads();
            }
        }

        // ---- flush hob -> out, coalesced float4 (drains at next block's barrier;
        //      earliest global re-read of these rows is 3 blocks later) ----
        {
            const int nf4 = (tend - t0) * (RR / 4);       // 1536, or 512 in last block
            const float4* src = (const float4*)&hob[0][0];
            float4* dst = (float4*)(outw + (size_t)t0 * RR);
#pragma unroll
            for (int it = 0; it < 3; ++it) {
                int idx = it * NTHR + tid;
                if (idx < nf4) dst[idx] = src[idx];
            }
        }
    }
}

extern "C" void kernel_launch(void* const* d_in, const int* in_sizes, int n_in,
                              void* d_out, int out_size, void* d_ws, size_t ws_size,
                              hipStream_t stream) {
    const float* x    = (const float*)d_in[0];   // (64, 2048, 1)
    const float* W_in = (const float*)d_in[1];   // (256, 1)
    const float* W_fb = (const float*)d_in[2];   // (5, 256, 256)
    const float* tapw = (const float*)d_in[3];   // (5,)
    const float* bias = (const float*)d_in[4];   // (256,)
    float* out = (float*)d_out;                  // (64, 2048, 256)
    unsigned short* bp = (unsigned short*)d_ws;  // 640 KB packed bf16 B-fragments

    pack_weights<<<160, 256, 0, stream>>>(W_fb, tapw, bp);
    reservoir_mfma<<<BB, NTHR, 0, stream>>>(x, W_in, bias, bp, out);
}